// Round 5
// baseline (584.037 us; speedup 1.0000x reference)
//
#include <hip/hip_runtime.h>

// x(64,512) -> emb(1024); h_i = (h_{i-1}+e_i)W^T + b; pred_mean = mean_i(Wc h_i + bc); CE.
// r_m = Wc*(stored W)^m. pred_sum[b,o] = sum_j <Acc_{512-j}[o,:], e_{b,j}> + <bsum[o,:],b>
//   Acc_M = sum_{m<=M} r_m,  bsum = 512*Wc + sum_m (512-m) r_m.
// Power-doubling levels k=2..10: one MFMA GEMM squares Q (rows<1024) and extends D
// rows; split-bf16 (hi/lo), 3 MFMA passes. v5: ws is ~500 MB (measured via fill
// kernel WRITE_SIZE) -> aggressive split-K (zs=8 small levels / 4 large);
// contract_k stages Acc once per j (Acc traffic 82->20 MB).
//
// ws (floats): C partials (up to 8 slabs x 1376 rows = 11,272,192) | csum | wpart |
// bsum | pred | part | u16 region. Total ~85 MB << 500 MB.
#define OFF_C    0L
#define OFF_CS   11272192L
#define OFF_WP   11354112L
#define OFF_BS   11436032L
#define OFF_PRED 11446272L
#define OFF_PART 11446912L
#define OFF_U16  11774592L
// u16 offsets (relative to ub):
#define UQAH 0L
#define UQAL 1048576L
#define UQATH 2097152L
#define UQATL 3145728L
#define UQBH 4194304L
#define UQBL 5242880L
#define UQBTH 6291456L
#define UQBTL 7340032L
#define URH  8388608L
#define URL  13631488L
#define CS8  1409024L    // C slab stride, zsplit=8 (rows<=1376)
#define CS4  2621440L    // C slab stride, zsplit=4 (rows<=2560)

typedef unsigned short u16;
typedef unsigned int u32;
typedef u16 us8 __attribute__((ext_vector_type(8)));
typedef short s8v __attribute__((ext_vector_type(8)));
typedef float f4v __attribute__((ext_vector_type(4)));

__device__ __forceinline__ u16 f2b(float f) {
    u32 u = __float_as_uint(f);
    return (u16)((u + 0x7fffu + ((u >> 16) & 1u)) >> 16);
}
__device__ __forceinline__ float b2f(u16 h) {
    return __uint_as_float((u32)h << 16);
}

// ---- split W (fp32) into bf16 hi/lo + transposed copies ----
__global__ __launch_bounds__(256) void split_w(
    const float* __restrict__ W, u16* __restrict__ Qh, u16* __restrict__ Ql,
    u16* __restrict__ QTh, u16* __restrict__ QTl)
{
    __shared__ u32 T[64][65];
    const int tid = threadIdx.x;
    const int r = tid >> 2, c0 = (tid & 3) << 4;
    alignas(16) u16 h[16], l[16];
    const size_t src = (size_t)(blockIdx.y * 64 + r) * 1024 + blockIdx.x * 64 + c0;
    #pragma unroll
    for (int q = 0; q < 4; q++) {
        float4 v = *(const float4*)(W + src + q * 4);
        float vv[4] = {v.x, v.y, v.z, v.w};
        #pragma unroll
        for (int i = 0; i < 4; i++) {
            u16 hh = f2b(vv[i]);
            u16 ll = f2b(vv[i] - b2f(hh));
            h[q * 4 + i] = hh; l[q * 4 + i] = ll;
            T[c0 + q * 4 + i][r] = ((u32)ll << 16) | hh;
        }
    }
    *(us8*)(Qh + src) = *(const us8*)&h[0];
    *(us8*)(Qh + src + 8) = *(const us8*)&h[8];
    *(us8*)(Ql + src) = *(const us8*)&l[0];
    *(us8*)(Ql + src + 8) = *(const us8*)&l[8];
    __syncthreads();
    alignas(16) u16 th[16], tl[16];
    #pragma unroll
    for (int i = 0; i < 16; i++) {
        u32 v = T[r][c0 + i];
        th[i] = (u16)(v & 0xffffu); tl[i] = (u16)(v >> 16);
    }
    const size_t dst = (size_t)(blockIdx.x * 64 + r) * 1024 + blockIdx.y * 64 + c0;
    *(us8*)(QTh + dst) = *(const us8*)&th[0];
    *(us8*)(QTh + dst + 8) = *(const us8*)&th[8];
    *(us8*)(QTl + dst) = *(const us8*)&tl[0];
    *(us8*)(QTl + dst + 8) = *(const us8*)&tl[8];
}

// ---- D0 = Wc*W partials (k-split by 8) -> pbuf[kz][10240] ----
__global__ __launch_bounds__(256) void thin_d0(
    const float* __restrict__ Wc, const float* __restrict__ W, float* __restrict__ pbuf)
{
    const int o = blockIdx.x >> 2;
    const int d = ((blockIdx.x & 3) << 8) + threadIdx.x;
    const int k0 = blockIdx.y << 7;
    float acc = 0.f;
    #pragma unroll 8
    for (int k = k0; k < k0 + 128; k++)
        acc = fmaf(Wc[o * 1024 + k], W[(size_t)k * 1024 + d], acc);
    pbuf[(size_t)blockIdx.y * 10240 + o * 1024 + d] = acc;
}

__global__ __launch_bounds__(256) void d0_fin(
    const float* __restrict__ pbuf, u16* __restrict__ Rh, u16* __restrict__ Rl)
{
    const int od = blockIdx.x * 256 + threadIdx.x;
    float v = 0.f;
    #pragma unroll
    for (int z = 0; z < 8; z++) v += pbuf[(size_t)z * 10240 + od];
    u16 h = f2b(v);
    Rh[od] = h;
    Rl[od] = f2b(v - b2f(h));
}

// ---- split-bf16 MFMA GEMM, split-K, fp32 partial output ----
// A rows [0,a1M) from Q(hi/lo); rows [a1M,M) from R rows 0..a2M. B transposed.
// 128x128 tile, 4 waves, 4x4 16x16x32 each, 3 passes. Register-prefetch pipeline.
// C[z][gr][1024] fp32, slab stride cS, z = blockIdx.z over kc-chunks.
__global__ __launch_bounds__(256) void gemm_mfma(
    const u16* __restrict__ Ah_g, const u16* __restrict__ Al_g,
    const u16* __restrict__ Rh_g, const u16* __restrict__ Rl_g,
    const u16* __restrict__ BTh_g, const u16* __restrict__ BTl_g,
    float* __restrict__ C, int a1M, int a2M, int kc, long cS)
{
    const int M = a1M + a2M;
    __shared__ alignas(16) u16 Ash[4][129][8], Asl[4][129][8];
    __shared__ alignas(16) u16 Bsh[4][129][8], Bsl[4][129][8];
    const int tid = threadIdx.x;
    const int bn = blockIdx.x << 7, bm = blockIdx.y << 7;
    const int kstart = blockIdx.z * kc, kend = kstart + kc;
    const int lane = tid & 63, wid = tid >> 6;
    const int wm = (wid & 1) << 6, wn = (wid >> 1) << 6;
    const int lrow = lane & 15, kq = lane >> 4;
    const int srow = tid >> 1;
    const int skq = (tid & 1) << 1;
    const int sk = skq << 3;

    const int gmA = bm + srow;
    const bool aval = (gmA < M);
    const u16* pAh; const u16* pAl;
    if (gmA < a1M) {
        pAh = Ah_g + (size_t)gmA * 1024;
        pAl = Al_g + (size_t)gmA * 1024;
    } else {
        int rr = aval ? (gmA - a1M) : 0;
        pAh = Rh_g + (size_t)rr * 1024;
        pAl = Rl_g + (size_t)rr * 1024;
    }
    const u16* pBh = BTh_g + (size_t)(bn + srow) * 1024;
    const u16* pBl = BTl_g + (size_t)(bn + srow) * 1024;

    f4v acc[4][4];
    #pragma unroll
    for (int i = 0; i < 4; i++)
        #pragma unroll
        for (int j = 0; j < 4; j++) acc[i][j] = 0.f;

    us8 ah0, ah1, al0, al1, bh0, bh1, bl0, bl1;
    auto loadstep = [&](int k) {
        if (aval) {
            ah0 = *(const us8*)(pAh + k + sk); ah1 = *(const us8*)(pAh + k + sk + 8);
            al0 = *(const us8*)(pAl + k + sk); al1 = *(const us8*)(pAl + k + sk + 8);
        } else { ah0 = 0; ah1 = 0; al0 = 0; al1 = 0; }
        bh0 = *(const us8*)(pBh + k + sk); bh1 = *(const us8*)(pBh + k + sk + 8);
        bl0 = *(const us8*)(pBl + k + sk); bl1 = *(const us8*)(pBl + k + sk + 8);
    };
    loadstep(kstart);

    for (int k0 = kstart; k0 < kend; k0 += 32) {
        *(us8*)&Ash[skq][srow][0] = ah0;
        *(us8*)&Ash[skq + 1][srow][0] = ah1;
        *(us8*)&Asl[skq][srow][0] = al0;
        *(us8*)&Asl[skq + 1][srow][0] = al1;
        *(us8*)&Bsh[skq][srow][0] = bh0;
        *(us8*)&Bsh[skq + 1][srow][0] = bh1;
        *(us8*)&Bsl[skq][srow][0] = bl0;
        *(us8*)&Bsl[skq + 1][srow][0] = bl1;
        __syncthreads();
        if (k0 + 32 < kend) loadstep(k0 + 32);   // prefetch overlaps MFMA below
        s8v afh[4], afl[4], bfh[4], bfl[4];
        #pragma unroll
        for (int i = 0; i < 4; i++) {
            afh[i] = *(const s8v*)&Ash[kq][wm + (i << 4) + lrow][0];
            afl[i] = *(const s8v*)&Asl[kq][wm + (i << 4) + lrow][0];
            bfh[i] = *(const s8v*)&Bsh[kq][wn + (i << 4) + lrow][0];
            bfl[i] = *(const s8v*)&Bsl[kq][wn + (i << 4) + lrow][0];
        }
        #pragma unroll
        for (int mi = 0; mi < 4; mi++)
            #pragma unroll
            for (int ni = 0; ni < 4; ni++) {
                acc[mi][ni] = __builtin_amdgcn_mfma_f32_16x16x32_bf16(
                    afh[mi], bfh[ni], acc[mi][ni], 0, 0, 0);
                acc[mi][ni] = __builtin_amdgcn_mfma_f32_16x16x32_bf16(
                    afl[mi], bfh[ni], acc[mi][ni], 0, 0, 0);
                acc[mi][ni] = __builtin_amdgcn_mfma_f32_16x16x32_bf16(
                    afh[mi], bfl[ni], acc[mi][ni], 0, 0, 0);
            }
        __syncthreads();
    }
    float* Cz = C + (size_t)blockIdx.z * cS;
    #pragma unroll
    for (int mi = 0; mi < 4; mi++)
        #pragma unroll
        for (int i = 0; i < 4; i++) {
            const int gr = bm + wm + (mi << 4) + (kq << 2) + i;
            if (gr >= M) continue;
            #pragma unroll
            for (int ni = 0; ni < 4; ni++)
                Cz[(size_t)gr * 1024 + bn + wn + (ni << 4) + lrow] = acc[mi][ni][i];
        }
}

// ---- combine: sum z slabs, split hi/lo; Q rows -> Qh/Ql + fused-transpose QT;
//      D rows -> R rows (gr - a1M + a2M). 64x64 tile per block. ----
__global__ __launch_bounds__(256) void combine(
    const float* __restrict__ C, int zsplit, long cS, int a1M, int a2M, int M,
    u16* __restrict__ Qh, u16* __restrict__ Ql,
    u16* __restrict__ QTh, u16* __restrict__ QTl,
    u16* __restrict__ Rh, u16* __restrict__ Rl)
{
    __shared__ u32 T[64][65];
    const int tid = threadIdx.x;
    const int r = tid >> 2, c0 = (tid & 3) << 4;
    const int row0 = blockIdx.y << 6, col0 = blockIdx.x << 6;
    const int gr = row0 + r;
    const bool isQ = (row0 < a1M);
    alignas(16) u16 h[16], l[16];
    #pragma unroll
    for (int q = 0; q < 4; q++) {
        float4 v = make_float4(0.f, 0.f, 0.f, 0.f);
        if (gr < M) {
            const float* p = C + (size_t)gr * 1024 + col0 + c0 + q * 4;
            v = *(const float4*)p;
            for (int z = 1; z < zsplit; z++) {
                float4 t = *(const float4*)(p + (size_t)z * cS);
                v.x += t.x; v.y += t.y; v.z += t.z; v.w += t.w;
            }
        }
        float vv[4] = {v.x, v.y, v.z, v.w};
        #pragma unroll
        for (int i = 0; i < 4; i++) {
            u16 hh = f2b(vv[i]);
            u16 ll = f2b(vv[i] - b2f(hh));
            h[q * 4 + i] = hh; l[q * 4 + i] = ll;
            if (isQ) T[c0 + q * 4 + i][r] = ((u32)ll << 16) | hh;
        }
    }
    if (isQ) {
        const size_t dst = (size_t)gr * 1024 + col0 + c0;
        *(us8*)(Qh + dst) = *(const us8*)&h[0];
        *(us8*)(Qh + dst + 8) = *(const us8*)&h[8];
        *(us8*)(Ql + dst) = *(const us8*)&l[0];
        *(us8*)(Ql + dst + 8) = *(const us8*)&l[8];
        __syncthreads();
        alignas(16) u16 th[16], tl[16];
        #pragma unroll
        for (int i = 0; i < 16; i++) {
            u32 v = T[r][c0 + i];
            th[i] = (u16)(v & 0xffffu); tl[i] = (u16)(v >> 16);
        }
        const size_t dt = (size_t)(col0 + r) * 1024 + row0 + c0;
        *(us8*)(QTh + dt) = *(const us8*)&th[0];
        *(us8*)(QTh + dt + 8) = *(const us8*)&th[8];
        *(us8*)(QTl + dt) = *(const us8*)&tl[0];
        *(us8*)(QTl + dt + 8) = *(const us8*)&tl[8];
    } else if (gr < M) {
        const size_t dst = (size_t)(gr - a1M + a2M) * 1024 + col0 + c0;
        *(us8*)(Rh + dst) = *(const us8*)&h[0];
        *(us8*)(Rh + dst + 8) = *(const us8*)&h[8];
        *(us8*)(Rl + dst) = *(const us8*)&l[0];
        *(us8*)(Rl + dst + 8) = *(const us8*)&l[8];
    }
}

// ---- prefix pass1: chunk sums + weighted sums ----
__global__ __launch_bounds__(256) void prefix_pass1(
    const u16* __restrict__ Rh, const u16* __restrict__ Rl,
    float* __restrict__ csum, float* __restrict__ wpart)
{
    const int od = blockIdx.x * 256 + threadIdx.x;
    const int c = blockIdx.y;
    const u16* ph = Rh + (size_t)(c * 64) * 10240 + od;
    const u16* pl = Rl + (size_t)(c * 64) * 10240 + od;
    float cs = 0.f, wsv = 0.f;
    #pragma unroll 4
    for (int i = 0; i < 64; i++) {
        float v = b2f(ph[(size_t)i * 10240]) + b2f(pl[(size_t)i * 10240]);
        cs += v;
        wsv += (float)(511 - (c * 64 + i)) * v;
    }
    csum[c * 10240 + od] = cs;
    wpart[c * 10240 + od] = wsv;
}

// ---- prefix pass2: Acc_m fp32 ----
__global__ __launch_bounds__(256) void prefix_pass2(
    const u16* __restrict__ Rh, const u16* __restrict__ Rl,
    const float* __restrict__ csum, float* __restrict__ Acc)
{
    const int od = blockIdx.x * 256 + threadIdx.x;
    const int c = blockIdx.y;
    float run = 0.f;
    #pragma unroll
    for (int c2 = 0; c2 < 8; c2++) {
        float t = csum[c2 * 10240 + od];
        run += (c2 < c) ? t : 0.f;
    }
    const u16* ph = Rh + (size_t)(c * 64) * 10240 + od;
    const u16* pl = Rl + (size_t)(c * 64) * 10240 + od;
    float* pa = Acc + (size_t)(c * 64) * 10240 + od;
    #pragma unroll 4
    for (int i = 0; i < 64; i++) {
        run += b2f(ph[(size_t)i * 10240]) + b2f(pl[(size_t)i * 10240]);
        pa[(size_t)i * 10240] = run;
    }
}

__global__ __launch_bounds__(256) void bsum_k(
    const float* __restrict__ wpart, const float* __restrict__ Wc, float* __restrict__ bsum)
{
    const int od = blockIdx.x * 256 + threadIdx.x;
    float s = 512.f * Wc[od];
    #pragma unroll
    for (int c = 0; c < 8; c++) s += wpart[c * 10240 + od];
    bsum[od] = s;
}

// ---- contract v3: WG per j; Acc staged once; 4 chunks x 16 b; wave owns 4 b. ----
__global__ __launch_bounds__(256) void contract_k(
    const float* __restrict__ Acc, const int* __restrict__ x,
    const float* __restrict__ emb, float* __restrict__ part)
{
    __shared__ float As[10240];
    const int tid = threadIdx.x;
    const int j = blockIdx.x;
    const int w = tid >> 6, lane = tid & 63;
    const float4* emb4 = (const float4*)emb;
    float4* As4 = (float4*)As;
    const float4* Ap = (const float4*)(Acc + (size_t)(511 - j) * 10240);

    // chunk-0 embedding loads (wave w owns batch rows chunk*16 + w*4 .. +3)
    int i0 = x[((w << 2) + 0) * 512 + j], i1 = x[((w << 2) + 1) * 512 + j];
    int i2 = x[((w << 2) + 2) * 512 + j], i3 = x[((w << 2) + 3) * 512 + j];
    float4 e0[4], e1[4], e2[4], e3[4];
    #pragma unroll
    for (int c = 0; c < 4; c++) {
        e0[c] = emb4[(size_t)i0 * 256 + (c << 6) + lane];
        e1[c] = emb4[(size_t)i1 * 256 + (c << 6) + lane];
        e2[c] = emb4[(size_t)i2 * 256 + (c << 6) + lane];
        e3[c] = emb4[(size_t)i3 * 256 + (c << 6) + lane];
    }
    #pragma unroll
    for (int i = 0; i < 10; i++) As4[tid + (i << 8)] = Ap[tid + (i << 8)];
    __syncthreads();

    for (int chunk = 0; chunk < 4; chunk++) {
        float p0[10], p1[10], p2[10], p3[10];
        #pragma unroll
        for (int o = 0; o < 10; o++) {
            float s0 = 0.f, s1 = 0.f, s2 = 0.f, s3 = 0.f;
            #pragma unroll
            for (int c = 0; c < 4; c++) {
                float4 a = As4[(o << 8) + (c << 6) + lane];
                s0 = fmaf(a.x, e0[c].x, s0); s0 = fmaf(a.y, e0[c].y, s0);
                s0 = fmaf(a.z, e0[c].z, s0); s0 = fmaf(a.w, e0[c].w, s0);
                s1 = fmaf(a.x, e1[c].x, s1); s1 = fmaf(a.y, e1[c].y, s1);
                s1 = fmaf(a.z, e1[c].z, s1); s1 = fmaf(a.w, e1[c].w, s1);
                s2 = fmaf(a.x, e2[c].x, s2); s2 = fmaf(a.y, e2[c].y, s2);
                s2 = fmaf(a.z, e2[c].z, s2); s2 = fmaf(a.w, e2[c].w, s2);
                s3 = fmaf(a.x, e3[c].x, s3); s3 = fmaf(a.y, e3[c].y, s3);
                s3 = fmaf(a.z, e3[c].z, s3); s3 = fmaf(a.w, e3[c].w, s3);
            }
            p0[o] = s0; p1[o] = s1; p2[o] = s2; p3[o] = s3;
        }
        // prefetch next chunk's e-rows into the now-dead e registers;
        // the shuffle-reduce below hides the load latency.
        if (chunk < 3) {
            const int bn = ((chunk + 1) << 4) + (w << 2);
            i0 = x[(bn + 0) * 512 + j]; i1 = x[(bn + 1) * 512 + j];
            i2 = x[(bn + 2) * 512 + j]; i3 = x[(bn + 3) * 512 + j];
            #pragma unroll
            for (int c = 0; c < 4; c++) {
                e0[c] = emb4[(size_t)i0 * 256 + (c << 6) + lane];
                e1[c] = emb4[(size_t)i1 * 256 + (c << 6) + lane];
                e2[c] = emb4[(size_t)i2 * 256 + (c << 6) + lane];
                e3[c] = emb4[(size_t)i3 * 256 + (c << 6) + lane];
            }
        }
        #pragma unroll
        for (int o = 0; o < 10; o++) {
            #pragma unroll
            for (int off = 32; off; off >>= 1) {
                p0[o] += __shfl_down(p0[o], off);
                p1[o] += __shfl_down(p1[o], off);
                p2[o] += __shfl_down(p2[o], off);
                p3[o] += __shfl_down(p3[o], off);
            }
        }
        if (lane == 0) {
            const int bbase = (chunk << 4) + (w << 2);
            float* pp = part + (size_t)j * 640 + bbase * 10;
            #pragma unroll
            for (int o = 0; o < 10; o++) {
                pp[o] = p0[o]; pp[10 + o] = p1[o];
                pp[20 + o] = p2[o]; pp[30 + o] = p3[o];
            }
        }
    }
}

__global__ __launch_bounds__(256) void reduce_part(
    const float* __restrict__ part, float* __restrict__ pred)
{
    const int gid = blockIdx.x * 256 + threadIdx.x;
    const int out = gid >> 4, s = gid & 15;
    float p = 0.f;
    #pragma unroll 8
    for (int t = 0; t < 32; t++) p += part[(size_t)(s + (t << 4)) * 640 + out];
    for (int off = 8; off; off >>= 1) p += __shfl_down(p, off, 16);
    if (s == 0) pred[out] = p;
}

__global__ __launch_bounds__(640) void finalize_k(
    const float* __restrict__ pred, const float* __restrict__ bsum,
    const float* __restrict__ bvec, const float* __restrict__ bc,
    const int* __restrict__ label, float* __restrict__ out)
{
    __shared__ float biasv[10];
    const int tid = threadIdx.x;
    {
        int o = tid >> 6, lane = tid & 63;
        float s = 0.f;
        for (int k = lane; k < 1024; k += 64) s = fmaf(bsum[o * 1024 + k], bvec[k], s);
        for (int off = 32; off; off >>= 1) s += __shfl_down(s, off, 64);
        if (lane == 0) biasv[o] = s;
    }
    __syncthreads();
    if (tid < 64) {
        int b = tid, lab = label[b];
        float v[10], mx = -1e30f;
        #pragma unroll
        for (int o = 0; o < 10; o++) {
            v[o] = (pred[b * 10 + o] + biasv[o]) * (1.f / 512.f) + bc[o];
            mx = fmaxf(mx, v[o]);
        }
        float se = 0.f, vl = 0.f;
        #pragma unroll
        for (int o = 0; o < 10; o++) {
            se += __expf(v[o] - mx);
            if (o == lab) vl = v[o];
        }
        float myloss = (mx + __logf(se)) - vl;
        for (int off = 32; off; off >>= 1) myloss += __shfl_down(myloss, off, 64);
        if (tid == 0) out[0] = myloss * (1.f / 64.f);
    }
}

extern "C" void kernel_launch(void* const* d_in, const int* in_sizes, int n_in,
                              void* d_out, int out_size, void* d_ws, size_t ws_size,
                              hipStream_t stream) {
    const int*   x     = (const int*)d_in[0];
    const int*   label = (const int*)d_in[1];
    const float* emb   = (const float*)d_in[2];
    const float* W     = (const float*)d_in[3];
    const float* bvec  = (const float*)d_in[4];
    const float* Wc    = (const float*)d_in[5];
    const float* bc    = (const float*)d_in[6];
    float* ws    = (float*)d_ws;
    float* C     = ws + OFF_C;
    float* Acc   = ws + OFF_C;          // overlay: used after last combine
    float* csum  = ws + OFF_CS;
    float* wpart = ws + OFF_WP;
    float* bsum  = ws + OFF_BS;
    float* pred  = ws + OFF_PRED;
    float* part  = ws + OFF_PART;
    u16*   ub    = (u16*)(ws + OFF_U16);
    u16* RH = ub + URH;
    u16* RL = ub + URL;
    u16* qin[4]  = {ub + UQAH, ub + UQAL, ub + UQATH, ub + UQATL};
    u16* qout[4] = {ub + UQBH, ub + UQBL, ub + UQBTH, ub + UQBTL};
    float* out   = (float*)d_out;

    split_w<<<dim3(16, 16), 256, 0, stream>>>(W, qin[0], qin[1], qin[2], qin[3]);
    thin_d0<<<dim3(40, 8), 256, 0, stream>>>(Wc, W, C);
    d0_fin<<<40, 256, 0, stream>>>(C, RH, RL);

    int a2M = 10;
    for (int k = 2; k <= 10; k++) {
        const int a1M = (k < 10) ? 1024 : 0;
        const int M = a1M + a2M;
        const int zs = (M <= 1376) ? 8 : 4;
        const long cS = (zs == 8) ? CS8 : CS4;
        const int kc = 1024 / zs;
        dim3 g(8, (M + 127) / 128, zs);
        gemm_mfma<<<g, 256, 0, stream>>>(qin[0], qin[1], RH, RL, qin[2], qin[3],
                                         C, a1M, a2M, kc, cS);
        combine<<<dim3(16, (M + 63) / 64), 256, 0, stream>>>(
            C, zs, cS, a1M, a2M, M,
            qout[0], qout[1], qout[2], qout[3], RH, RL);
        for (int i = 0; i < 4; i++) { u16* t = qin[i]; qin[i] = qout[i]; qout[i] = t; }
        a2M <<= 1;
    }

    prefix_pass1<<<dim3(40, 8), 256, 0, stream>>>(RH, RL, csum, wpart);
    prefix_pass2<<<dim3(40, 8), 256, 0, stream>>>(RH, RL, csum, Acc);
    bsum_k<<<40, 256, 0, stream>>>(wpart, Wc, bsum);
    contract_k<<<512, 256, 0, stream>>>(Acc, x, emb, part);
    reduce_part<<<40, 256, 0, stream>>>(part, pred);
    finalize_k<<<1, 640, 0, stream>>>(pred, bsum, bvec, bc, label, out);
}

// Round 6
// 504.303 us; speedup vs baseline: 1.1581x; 1.1581x over previous
//
#include <hip/hip_runtime.h>

// x(64,512) -> emb(1024); h_i = (h_{i-1}+e_i)W^T + b; pred_mean = mean_i(Wc h_i + bc); CE.
// r_m = Wc*(stored W)^m. pred_sum[b,o] = sum_j <Acc_{512-j}[o,:], e_{b,j}> + <bsum[o,:],b>
//   Acc_M = sum_{m<=M} r_m,  bsum = 512*Wc + sum_m (512-m) r_m.
// Power-doubling levels k=2..10: one MFMA GEMM squares Q (rows<1024, split-bf16 hi/lo,
// 3 passes) and extends D rows (bf16-single storage, 2 passes: Dh*Qh + Dh*Ql —
// r_m errors enter the loss linearly, no squaring amplification; measured headroom
// is ~6 orders of magnitude). v6: split-K reverted to round-4 zs (4 small / 2 large).
//
// ws (floats): C partials | csum | wpart | bsum | pred | part | u16 region. ~75 MB.
#define OFF_C    0L
#define OFF_CS   11272192L
#define OFF_WP   11354112L
#define OFF_BS   11436032L
#define OFF_PRED 11446272L
#define OFF_PART 11446912L
#define OFF_U16  11774592L
// u16 offsets (relative to ub):
#define UQAH 0L
#define UQAL 1048576L
#define UQATH 2097152L
#define UQATL 3145728L
#define UQBH 4194304L
#define UQBL 5242880L
#define UQBTH 6291456L
#define UQBTL 7340032L
#define URH  8388608L        // Rh [5120][1024] bf16 (no lo plane anymore)
#define CSA  1409024L        // C slab stride, zs=4 levels (rows<=1376)
#define CSB  2621440L        // C slab stride, zs=2 levels (rows<=2560)

typedef unsigned short u16;
typedef unsigned int u32;
typedef u16 us8 __attribute__((ext_vector_type(8)));
typedef short s8v __attribute__((ext_vector_type(8)));
typedef float f4v __attribute__((ext_vector_type(4)));

__device__ __forceinline__ u16 f2b(float f) {
    u32 u = __float_as_uint(f);
    return (u16)((u + 0x7fffu + ((u >> 16) & 1u)) >> 16);
}
__device__ __forceinline__ float b2f(u16 h) {
    return __uint_as_float((u32)h << 16);
}

// ---- split W (fp32) into bf16 hi/lo + transposed copies ----
__global__ __launch_bounds__(256) void split_w(
    const float* __restrict__ W, u16* __restrict__ Qh, u16* __restrict__ Ql,
    u16* __restrict__ QTh, u16* __restrict__ QTl)
{
    __shared__ u32 T[64][65];
    const int tid = threadIdx.x;
    const int r = tid >> 2, c0 = (tid & 3) << 4;
    alignas(16) u16 h[16], l[16];
    const size_t src = (size_t)(blockIdx.y * 64 + r) * 1024 + blockIdx.x * 64 + c0;
    #pragma unroll
    for (int q = 0; q < 4; q++) {
        float4 v = *(const float4*)(W + src + q * 4);
        float vv[4] = {v.x, v.y, v.z, v.w};
        #pragma unroll
        for (int i = 0; i < 4; i++) {
            u16 hh = f2b(vv[i]);
            u16 ll = f2b(vv[i] - b2f(hh));
            h[q * 4 + i] = hh; l[q * 4 + i] = ll;
            T[c0 + q * 4 + i][r] = ((u32)ll << 16) | hh;
        }
    }
    *(us8*)(Qh + src) = *(const us8*)&h[0];
    *(us8*)(Qh + src + 8) = *(const us8*)&h[8];
    *(us8*)(Ql + src) = *(const us8*)&l[0];
    *(us8*)(Ql + src + 8) = *(const us8*)&l[8];
    __syncthreads();
    alignas(16) u16 th[16], tl[16];
    #pragma unroll
    for (int i = 0; i < 16; i++) {
        u32 v = T[r][c0 + i];
        th[i] = (u16)(v & 0xffffu); tl[i] = (u16)(v >> 16);
    }
    const size_t dst = (size_t)(blockIdx.x * 64 + r) * 1024 + blockIdx.y * 64 + c0;
    *(us8*)(QTh + dst) = *(const us8*)&th[0];
    *(us8*)(QTh + dst + 8) = *(const us8*)&th[8];
    *(us8*)(QTl + dst) = *(const us8*)&tl[0];
    *(us8*)(QTl + dst + 8) = *(const us8*)&tl[8];
}

// ---- D0 = Wc*W partials (k-split by 8) -> pbuf[kz][10240] ----
__global__ __launch_bounds__(256) void thin_d0(
    const float* __restrict__ Wc, const float* __restrict__ W, float* __restrict__ pbuf)
{
    const int o = blockIdx.x >> 2;
    const int d = ((blockIdx.x & 3) << 8) + threadIdx.x;
    const int k0 = blockIdx.y << 7;
    float acc = 0.f;
    #pragma unroll 8
    for (int k = k0; k < k0 + 128; k++)
        acc = fmaf(Wc[o * 1024 + k], W[(size_t)k * 1024 + d], acc);
    pbuf[(size_t)blockIdx.y * 10240 + o * 1024 + d] = acc;
}

__global__ __launch_bounds__(256) void d0_fin(
    const float* __restrict__ pbuf, u16* __restrict__ Rh)
{
    const int od = blockIdx.x * 256 + threadIdx.x;
    float v = 0.f;
    #pragma unroll
    for (int z = 0; z < 8; z++) v += pbuf[(size_t)z * 10240 + od];
    Rh[od] = f2b(v);
}

// ---- MFMA GEMM, split-K, fp32 partial output ----
// Q blocks (bm < a1M): A = Q hi/lo, 3 passes. D blocks: A = Rh (bf16 single),
// 2 passes (Ah*Bh + Ah*Bl). B transposed, hi/lo. 128x128 tile, 4 waves,
// 4x4 16x16x32/wave. Register-prefetch pipeline. C[z][gr][1024] fp32 slab stride cS.
__global__ __launch_bounds__(256) void gemm_mfma(
    const u16* __restrict__ Ah_g, const u16* __restrict__ Al_g,
    const u16* __restrict__ Rh_g,
    const u16* __restrict__ BTh_g, const u16* __restrict__ BTl_g,
    float* __restrict__ C, int a1M, int a2M, int kc, long cS)
{
    const int M = a1M + a2M;
    __shared__ alignas(16) u16 Ash[4][129][8], Asl[4][129][8];
    __shared__ alignas(16) u16 Bsh[4][129][8], Bsl[4][129][8];
    const int tid = threadIdx.x;
    const int bn = blockIdx.x << 7, bm = blockIdx.y << 7;
    const int kstart = blockIdx.z * kc, kend = kstart + kc;
    const int lane = tid & 63, wid = tid >> 6;
    const int wm = (wid & 1) << 6, wn = (wid >> 1) << 6;
    const int lrow = lane & 15, kq = lane >> 4;
    const int srow = tid >> 1;
    const int skq = (tid & 1) << 1;
    const int sk = skq << 3;

    const u16* pBh = BTh_g + (size_t)(bn + srow) * 1024;
    const u16* pBl = BTl_g + (size_t)(bn + srow) * 1024;

    f4v acc[4][4];
    #pragma unroll
    for (int i = 0; i < 4; i++)
        #pragma unroll
        for (int j = 0; j < 4; j++) acc[i][j] = 0.f;

    if (bm < a1M) {
        // ---------------- Q path: 3-pass, no row guard (a1M tile-aligned) ----------
        const u16* pAh = Ah_g + (size_t)(bm + srow) * 1024;
        const u16* pAl = Al_g + (size_t)(bm + srow) * 1024;
        us8 ah0, ah1, al0, al1, bh0, bh1, bl0, bl1;
        auto loadstep = [&](int k) {
            ah0 = *(const us8*)(pAh + k + sk); ah1 = *(const us8*)(pAh + k + sk + 8);
            al0 = *(const us8*)(pAl + k + sk); al1 = *(const us8*)(pAl + k + sk + 8);
            bh0 = *(const us8*)(pBh + k + sk); bh1 = *(const us8*)(pBh + k + sk + 8);
            bl0 = *(const us8*)(pBl + k + sk); bl1 = *(const us8*)(pBl + k + sk + 8);
        };
        loadstep(kstart);
        for (int k0 = kstart; k0 < kend; k0 += 32) {
            *(us8*)&Ash[skq][srow][0] = ah0;
            *(us8*)&Ash[skq + 1][srow][0] = ah1;
            *(us8*)&Asl[skq][srow][0] = al0;
            *(us8*)&Asl[skq + 1][srow][0] = al1;
            *(us8*)&Bsh[skq][srow][0] = bh0;
            *(us8*)&Bsh[skq + 1][srow][0] = bh1;
            *(us8*)&Bsl[skq][srow][0] = bl0;
            *(us8*)&Bsl[skq + 1][srow][0] = bl1;
            __syncthreads();
            if (k0 + 32 < kend) loadstep(k0 + 32);
            s8v afh[4], afl[4], bfh[4], bfl[4];
            #pragma unroll
            for (int i = 0; i < 4; i++) {
                afh[i] = *(const s8v*)&Ash[kq][wm + (i << 4) + lrow][0];
                afl[i] = *(const s8v*)&Asl[kq][wm + (i << 4) + lrow][0];
                bfh[i] = *(const s8v*)&Bsh[kq][wn + (i << 4) + lrow][0];
                bfl[i] = *(const s8v*)&Bsl[kq][wn + (i << 4) + lrow][0];
            }
            #pragma unroll
            for (int mi = 0; mi < 4; mi++)
                #pragma unroll
                for (int ni = 0; ni < 4; ni++) {
                    acc[mi][ni] = __builtin_amdgcn_mfma_f32_16x16x32_bf16(
                        afh[mi], bfh[ni], acc[mi][ni], 0, 0, 0);
                    acc[mi][ni] = __builtin_amdgcn_mfma_f32_16x16x32_bf16(
                        afl[mi], bfh[ni], acc[mi][ni], 0, 0, 0);
                    acc[mi][ni] = __builtin_amdgcn_mfma_f32_16x16x32_bf16(
                        afh[mi], bfl[ni], acc[mi][ni], 0, 0, 0);
                }
            __syncthreads();
        }
    } else {
        // ---------------- D path: 2-pass, A = Rh single-bf16 ----------------------
        const int rr = bm + srow - a1M;
        const bool aval = (rr < a2M);
        const u16* pAh = Rh_g + (size_t)(aval ? rr : 0) * 1024;
        us8 ah0, ah1, bh0, bh1, bl0, bl1;
        auto loadstep = [&](int k) {
            if (aval) {
                ah0 = *(const us8*)(pAh + k + sk); ah1 = *(const us8*)(pAh + k + sk + 8);
            } else { ah0 = 0; ah1 = 0; }
            bh0 = *(const us8*)(pBh + k + sk); bh1 = *(const us8*)(pBh + k + sk + 8);
            bl0 = *(const us8*)(pBl + k + sk); bl1 = *(const us8*)(pBl + k + sk + 8);
        };
        loadstep(kstart);
        for (int k0 = kstart; k0 < kend; k0 += 32) {
            *(us8*)&Ash[skq][srow][0] = ah0;
            *(us8*)&Ash[skq + 1][srow][0] = ah1;
            *(us8*)&Bsh[skq][srow][0] = bh0;
            *(us8*)&Bsh[skq + 1][srow][0] = bh1;
            *(us8*)&Bsl[skq][srow][0] = bl0;
            *(us8*)&Bsl[skq + 1][srow][0] = bl1;
            __syncthreads();
            if (k0 + 32 < kend) loadstep(k0 + 32);
            s8v afh[4], bfh[4], bfl[4];
            #pragma unroll
            for (int i = 0; i < 4; i++) {
                afh[i] = *(const s8v*)&Ash[kq][wm + (i << 4) + lrow][0];
                bfh[i] = *(const s8v*)&Bsh[kq][wn + (i << 4) + lrow][0];
                bfl[i] = *(const s8v*)&Bsl[kq][wn + (i << 4) + lrow][0];
            }
            #pragma unroll
            for (int mi = 0; mi < 4; mi++)
                #pragma unroll
                for (int ni = 0; ni < 4; ni++) {
                    acc[mi][ni] = __builtin_amdgcn_mfma_f32_16x16x32_bf16(
                        afh[mi], bfh[ni], acc[mi][ni], 0, 0, 0);
                    acc[mi][ni] = __builtin_amdgcn_mfma_f32_16x16x32_bf16(
                        afh[mi], bfl[ni], acc[mi][ni], 0, 0, 0);
                }
            __syncthreads();
        }
    }
    float* Cz = C + (size_t)blockIdx.z * cS;
    #pragma unroll
    for (int mi = 0; mi < 4; mi++)
        #pragma unroll
        for (int i = 0; i < 4; i++) {
            const int gr = bm + wm + (mi << 4) + (kq << 2) + i;
            if (gr >= M) continue;
            #pragma unroll
            for (int ni = 0; ni < 4; ni++)
                Cz[(size_t)gr * 1024 + bn + wn + (ni << 4) + lrow] = acc[mi][ni][i];
        }
}

// ---- combine: sum z slabs; Q rows -> hi/lo + fused-transpose; D rows -> Rh only ----
__global__ __launch_bounds__(256) void combine(
    const float* __restrict__ C, int zsplit, long cS, int a1M, int a2M, int M,
    u16* __restrict__ Qh, u16* __restrict__ Ql,
    u16* __restrict__ QTh, u16* __restrict__ QTl,
    u16* __restrict__ Rh)
{
    __shared__ u32 T[64][65];
    const int tid = threadIdx.x;
    const int r = tid >> 2, c0 = (tid & 3) << 4;
    const int row0 = blockIdx.y << 6, col0 = blockIdx.x << 6;
    const int gr = row0 + r;
    const bool isQ = (row0 < a1M);
    alignas(16) u16 h[16], l[16];
    #pragma unroll
    for (int q = 0; q < 4; q++) {
        float4 v = make_float4(0.f, 0.f, 0.f, 0.f);
        if (gr < M) {
            const float* p = C + (size_t)gr * 1024 + col0 + c0 + q * 4;
            v = *(const float4*)p;
            for (int z = 1; z < zsplit; z++) {
                float4 t = *(const float4*)(p + (size_t)z * cS);
                v.x += t.x; v.y += t.y; v.z += t.z; v.w += t.w;
            }
        }
        float vv[4] = {v.x, v.y, v.z, v.w};
        #pragma unroll
        for (int i = 0; i < 4; i++) {
            u16 hh = f2b(vv[i]);
            u16 ll = f2b(vv[i] - b2f(hh));
            h[q * 4 + i] = hh; l[q * 4 + i] = ll;
            if (isQ) T[c0 + q * 4 + i][r] = ((u32)ll << 16) | hh;
        }
    }
    if (isQ) {
        const size_t dst = (size_t)gr * 1024 + col0 + c0;
        *(us8*)(Qh + dst) = *(const us8*)&h[0];
        *(us8*)(Qh + dst + 8) = *(const us8*)&h[8];
        *(us8*)(Ql + dst) = *(const us8*)&l[0];
        *(us8*)(Ql + dst + 8) = *(const us8*)&l[8];
        __syncthreads();
        alignas(16) u16 th[16], tl[16];
        #pragma unroll
        for (int i = 0; i < 16; i++) {
            u32 v = T[r][c0 + i];
            th[i] = (u16)(v & 0xffffu); tl[i] = (u16)(v >> 16);
        }
        const size_t dt = (size_t)(col0 + r) * 1024 + row0 + c0;
        *(us8*)(QTh + dt) = *(const us8*)&th[0];
        *(us8*)(QTh + dt + 8) = *(const us8*)&th[8];
        *(us8*)(QTl + dt) = *(const us8*)&tl[0];
        *(us8*)(QTl + dt + 8) = *(const us8*)&tl[8];
    } else if (gr < M) {
        const size_t dst = (size_t)(gr - a1M + a2M) * 1024 + col0 + c0;
        *(us8*)(Rh + dst) = *(const us8*)&h[0];
        *(us8*)(Rh + dst + 8) = *(const us8*)&h[8];
    }
}

// ---- prefix pass1: chunk sums + weighted sums ----
__global__ __launch_bounds__(256) void prefix_pass1(
    const u16* __restrict__ Rh, float* __restrict__ csum, float* __restrict__ wpart)
{
    const int od = blockIdx.x * 256 + threadIdx.x;
    const int c = blockIdx.y;
    const u16* ph = Rh + (size_t)(c * 64) * 10240 + od;
    float cs = 0.f, wsv = 0.f;
    #pragma unroll 4
    for (int i = 0; i < 64; i++) {
        float v = b2f(ph[(size_t)i * 10240]);
        cs += v;
        wsv += (float)(511 - (c * 64 + i)) * v;
    }
    csum[c * 10240 + od] = cs;
    wpart[c * 10240 + od] = wsv;
}

// ---- prefix pass2: Acc_m fp32 ----
__global__ __launch_bounds__(256) void prefix_pass2(
    const u16* __restrict__ Rh, const float* __restrict__ csum, float* __restrict__ Acc)
{
    const int od = blockIdx.x * 256 + threadIdx.x;
    const int c = blockIdx.y;
    float run = 0.f;
    #pragma unroll
    for (int c2 = 0; c2 < 8; c2++) {
        float t = csum[c2 * 10240 + od];
        run += (c2 < c) ? t : 0.f;
    }
    const u16* ph = Rh + (size_t)(c * 64) * 10240 + od;
    float* pa = Acc + (size_t)(c * 64) * 10240 + od;
    #pragma unroll 4
    for (int i = 0; i < 64; i++) {
        run += b2f(ph[(size_t)i * 10240]);
        pa[(size_t)i * 10240] = run;
    }
}

__global__ __launch_bounds__(256) void bsum_k(
    const float* __restrict__ wpart, const float* __restrict__ Wc, float* __restrict__ bsum)
{
    const int od = blockIdx.x * 256 + threadIdx.x;
    float s = 512.f * Wc[od];
    #pragma unroll
    for (int c = 0; c < 8; c++) s += wpart[c * 10240 + od];
    bsum[od] = s;
}

// ---- contract v3: WG per j; Acc staged once; 4 chunks x 16 b; wave owns 4 b. ----
__global__ __launch_bounds__(256) void contract_k(
    const float* __restrict__ Acc, const int* __restrict__ x,
    const float* __restrict__ emb, float* __restrict__ part)
{
    __shared__ float As[10240];
    const int tid = threadIdx.x;
    const int j = blockIdx.x;
    const int w = tid >> 6, lane = tid & 63;
    const float4* emb4 = (const float4*)emb;
    float4* As4 = (float4*)As;
    const float4* Ap = (const float4*)(Acc + (size_t)(511 - j) * 10240);

    int i0 = x[((w << 2) + 0) * 512 + j], i1 = x[((w << 2) + 1) * 512 + j];
    int i2 = x[((w << 2) + 2) * 512 + j], i3 = x[((w << 2) + 3) * 512 + j];
    float4 e0[4], e1[4], e2[4], e3[4];
    #pragma unroll
    for (int c = 0; c < 4; c++) {
        e0[c] = emb4[(size_t)i0 * 256 + (c << 6) + lane];
        e1[c] = emb4[(size_t)i1 * 256 + (c << 6) + lane];
        e2[c] = emb4[(size_t)i2 * 256 + (c << 6) + lane];
        e3[c] = emb4[(size_t)i3 * 256 + (c << 6) + lane];
    }
    #pragma unroll
    for (int i = 0; i < 10; i++) As4[tid + (i << 8)] = Ap[tid + (i << 8)];
    __syncthreads();

    for (int chunk = 0; chunk < 4; chunk++) {
        float p0[10], p1[10], p2[10], p3[10];
        #pragma unroll
        for (int o = 0; o < 10; o++) {
            float s0 = 0.f, s1 = 0.f, s2 = 0.f, s3 = 0.f;
            #pragma unroll
            for (int c = 0; c < 4; c++) {
                float4 a = As4[(o << 8) + (c << 6) + lane];
                s0 = fmaf(a.x, e0[c].x, s0); s0 = fmaf(a.y, e0[c].y, s0);
                s0 = fmaf(a.z, e0[c].z, s0); s0 = fmaf(a.w, e0[c].w, s0);
                s1 = fmaf(a.x, e1[c].x, s1); s1 = fmaf(a.y, e1[c].y, s1);
                s1 = fmaf(a.z, e1[c].z, s1); s1 = fmaf(a.w, e1[c].w, s1);
                s2 = fmaf(a.x, e2[c].x, s2); s2 = fmaf(a.y, e2[c].y, s2);
                s2 = fmaf(a.z, e2[c].z, s2); s2 = fmaf(a.w, e2[c].w, s2);
                s3 = fmaf(a.x, e3[c].x, s3); s3 = fmaf(a.y, e3[c].y, s3);
                s3 = fmaf(a.z, e3[c].z, s3); s3 = fmaf(a.w, e3[c].w, s3);
            }
            p0[o] = s0; p1[o] = s1; p2[o] = s2; p3[o] = s3;
        }
        if (chunk < 3) {
            const int bn = ((chunk + 1) << 4) + (w << 2);
            i0 = x[(bn + 0) * 512 + j]; i1 = x[(bn + 1) * 512 + j];
            i2 = x[(bn + 2) * 512 + j]; i3 = x[(bn + 3) * 512 + j];
            #pragma unroll
            for (int c = 0; c < 4; c++) {
                e0[c] = emb4[(size_t)i0 * 256 + (c << 6) + lane];
                e1[c] = emb4[(size_t)i1 * 256 + (c << 6) + lane];
                e2[c] = emb4[(size_t)i2 * 256 + (c << 6) + lane];
                e3[c] = emb4[(size_t)i3 * 256 + (c << 6) + lane];
            }
        }
        #pragma unroll
        for (int o = 0; o < 10; o++) {
            #pragma unroll
            for (int off = 32; off; off >>= 1) {
                p0[o] += __shfl_down(p0[o], off);
                p1[o] += __shfl_down(p1[o], off);
                p2[o] += __shfl_down(p2[o], off);
                p3[o] += __shfl_down(p3[o], off);
            }
        }
        if (lane == 0) {
            const int bbase = (chunk << 4) + (w << 2);
            float* pp = part + (size_t)j * 640 + bbase * 10;
            #pragma unroll
            for (int o = 0; o < 10; o++) {
                pp[o] = p0[o]; pp[10 + o] = p1[o];
                pp[20 + o] = p2[o]; pp[30 + o] = p3[o];
            }
        }
    }
}

__global__ __launch_bounds__(256) void reduce_part(
    const float* __restrict__ part, float* __restrict__ pred)
{
    const int gid = blockIdx.x * 256 + threadIdx.x;
    const int out = gid >> 4, s = gid & 15;
    float p = 0.f;
    #pragma unroll 8
    for (int t = 0; t < 32; t++) p += part[(size_t)(s + (t << 4)) * 640 + out];
    for (int off = 8; off; off >>= 1) p += __shfl_down(p, off, 16);
    if (s == 0) pred[out] = p;
}

__global__ __launch_bounds__(640) void finalize_k(
    const float* __restrict__ pred, const float* __restrict__ bsum,
    const float* __restrict__ bvec, const float* __restrict__ bc,
    const int* __restrict__ label, float* __restrict__ out)
{
    __shared__ float biasv[10];
    const int tid = threadIdx.x;
    {
        int o = tid >> 6, lane = tid & 63;
        float s = 0.f;
        for (int k = lane; k < 1024; k += 64) s = fmaf(bsum[o * 1024 + k], bvec[k], s);
        for (int off = 32; off; off >>= 1) s += __shfl_down(s, off, 64);
        if (lane == 0) biasv[o] = s;
    }
    __syncthreads();
    if (tid < 64) {
        int b = tid, lab = label[b];
        float v[10], mx = -1e30f;
        #pragma unroll
        for (int o = 0; o < 10; o++) {
            v[o] = (pred[b * 10 + o] + biasv[o]) * (1.f / 512.f) + bc[o];
            mx = fmaxf(mx, v[o]);
        }
        float se = 0.f, vl = 0.f;
        #pragma unroll
        for (int o = 0; o < 10; o++) {
            se += __expf(v[o] - mx);
            if (o == lab) vl = v[o];
        }
        float myloss = (mx + __logf(se)) - vl;
        for (int off = 32; off; off >>= 1) myloss += __shfl_down(myloss, off, 64);
        if (tid == 0) out[0] = myloss * (1.f / 64.f);
    }
}

extern "C" void kernel_launch(void* const* d_in, const int* in_sizes, int n_in,
                              void* d_out, int out_size, void* d_ws, size_t ws_size,
                              hipStream_t stream) {
    const int*   x     = (const int*)d_in[0];
    const int*   label = (const int*)d_in[1];
    const float* emb   = (const float*)d_in[2];
    const float* W     = (const float*)d_in[3];
    const float* bvec  = (const float*)d_in[4];
    const float* Wc    = (const float*)d_in[5];
    const float* bc    = (const float*)d_in[6];
    float* ws    = (float*)d_ws;
    float* C     = ws + OFF_C;
    float* Acc   = ws + OFF_C;          // overlay: used after last combine
    float* csum  = ws + OFF_CS;
    float* wpart = ws + OFF_WP;
    float* bsum  = ws + OFF_BS;
    float* pred  = ws + OFF_PRED;
    float* part  = ws + OFF_PART;
    u16*   ub    = (u16*)(ws + OFF_U16);
    u16* RH = ub + URH;
    u16* qin[4]  = {ub + UQAH, ub + UQAL, ub + UQATH, ub + UQATL};
    u16* qout[4] = {ub + UQBH, ub + UQBL, ub + UQBTH, ub + UQBTL};
    float* out   = (float*)d_out;

    split_w<<<dim3(16, 16), 256, 0, stream>>>(W, qin[0], qin[1], qin[2], qin[3]);
    thin_d0<<<dim3(40, 8), 256, 0, stream>>>(Wc, W, C);
    d0_fin<<<40, 256, 0, stream>>>(C, RH);

    int a2M = 10;
    for (int k = 2; k <= 10; k++) {
        const int a1M = (k < 10) ? 1024 : 0;
        const int M = a1M + a2M;
        const int zs = (M <= 1376) ? 4 : 2;
        const long cS = (zs == 4) ? CSA : CSB;
        const int kc = 1024 / zs;
        dim3 g(8, (M + 127) / 128, zs);
        gemm_mfma<<<g, 256, 0, stream>>>(qin[0], qin[1], RH, qin[2], qin[3],
                                         C, a1M, a2M, kc, cS);
        combine<<<dim3(16, (M + 63) / 64), 256, 0, stream>>>(
            C, zs, cS, a1M, a2M, M,
            qout[0], qout[1], qout[2], qout[3], RH);
        for (int i = 0; i < 4; i++) { u16* t = qin[i]; qin[i] = qout[i]; qout[i] = t; }
        a2M <<= 1;
    }

    prefix_pass1<<<dim3(40, 8), 256, 0, stream>>>(RH, csum, wpart);
    prefix_pass2<<<dim3(40, 8), 256, 0, stream>>>(RH, csum, Acc);
    bsum_k<<<40, 256, 0, stream>>>(wpart, Wc, bsum);
    contract_k<<<512, 256, 0, stream>>>(Acc, x, emb, part);
    reduce_part<<<40, 256, 0, stream>>>(part, pred);
    finalize_k<<<1, 640, 0, stream>>>(pred, bsum, bvec, bc, label, out);
}